// Round 1
// 508.863 us; speedup vs baseline: 1.6562x; 1.6562x over previous
//
#include <hip/hip_runtime.h>

#define NU     50000
#define NEN    100000
#define NEDGE  2000000
#define NINTER 1000000
#define CH     64
#define NRELM1 9
#define CAPE   64     // padded CSR bucket capacity per entity (Poisson(20): P(deg>=64)~6e-14/bin)
#define CAPU   64     // padded bucket capacity per user

typedef _Float16 hv2 __attribute__((ext_vector_type(2)));
typedef _Float16 h8  __attribute__((ext_vector_type(8)));
typedef float    f32x4 __attribute__((ext_vector_type(4)));
union P4 { float4 f; hv2 h[4]; };   // 16B = 8 halves

// ---- fused setup: embedding init + W transpose + padded-bucket edge scatter ----
// counters must be zeroed (hipMemsetAsync) before this kernel.
__global__ __launch_bounds__(256) void k_setup(
    const float* __restrict__ ue, const float* __restrict__ ee,
    const float* __restrict__ re, const float* __restrict__ wq,
    const float* __restrict__ iw, const int* __restrict__ eidx,
    const int* __restrict__ etype, const int* __restrict__ ii,
    _Float16* __restrict__ Eh, float* __restrict__ Eres, float* __restrict__ Ures,
    _Float16* __restrict__ Relh, _Float16* __restrict__ Wt,
    int* __restrict__ cntE, int* __restrict__ cntU,
    int* __restrict__ csrE, unsigned long long* __restrict__ csrU2)
{
    int i = blockIdx.x * 256 + threadIdx.x;           // grid covers NEN*CH
    if (i < NEN * CH) {
        float f = ee[i];
        Eh[i] = (_Float16)f;
        Eres[i] = f;
    }
    if (i < NU * CH)     Ures[i] = ue[i];
    if (i < NRELM1 * CH) Relh[i] = (_Float16)re[i];
    if (i < CH * CH)     Wt[(i & 63) * 64 + (i >> 6)] = (_Float16)wq[i];  // Wt[c][k] = W[k][c]
    if (i < NEDGE) {
        int head = eidx[i], tail = eidx[NEDGE + i], rt = etype[i] - 1;
        int pos = atomicAdd(&cntE[head], 1);
        if (pos < CAPE)
            __hip_atomic_store(&csrE[head * CAPE + pos], tail | (rt << 17),
                               __ATOMIC_RELAXED, __HIP_MEMORY_SCOPE_AGENT);
    }
    if (i < NINTER) {
        int u = ii[i], ent = ii[NINTER + i];
        int pos = atomicAdd(&cntU[u], 1);
        unsigned long long rec = (unsigned long long)(unsigned)ent
                               | ((unsigned long long)__float_as_uint(iw[i]) << 32);
        if (pos < CAPU)
            __hip_atomic_store(&csrU2[(size_t)u * CAPU + pos], rec,
                               __ATOMIC_RELAXED, __HIP_MEMORY_SCOPE_AGENT);
    }
}

// ---- Qh = Eh @ W via MFMA f16 (f32 accum). Wt is W transposed [c][k], f16.
// one wave = 16 rows x 64 cols; 4 waves/block = 64 rows/block. W stays L1-hot.
__global__ __launch_bounds__(256) void k_gemm(
    const _Float16* __restrict__ Eh, const _Float16* __restrict__ Wt,
    _Float16* __restrict__ Qh)
{
    int w = threadIdx.x >> 6, lane = threadIdx.x & 63;
    int r0 = blockIdx.x * 64 + w * 16;
    if (r0 >= NEN) return;                          // NEN%64==32: last 2 waves idle
    int lr = lane & 15, lg = lane >> 4;
    // A frag (16x32 K-chunk): lane holds row lr, k = kb*32 + lg*8 + j (8 contiguous)
    const _Float16* arow = Eh + (size_t)(r0 + lr) * 64 + lg * 8;
    h8 a0 = *(const h8*)(arow);
    h8 a1 = *(const h8*)(arow + 32);
#pragma unroll
    for (int ct = 0; ct < 4; ++ct) {
        // B frag: lane holds col ct*16+lr, k contiguous -> Wt row read
        const _Float16* brow = Wt + (ct * 16 + lr) * 64 + lg * 8;
        h8 b0 = *(const h8*)(brow);
        h8 b1 = *(const h8*)(brow + 32);
        f32x4 c = {0.f, 0.f, 0.f, 0.f};
        c = __builtin_amdgcn_mfma_f32_16x16x32_f16(a0, b0, c, 0, 0, 0);
        c = __builtin_amdgcn_mfma_f32_16x16x32_f16(a1, b1, c, 0, 0, 0);
        // C/D: col = lane&15, row = (lane>>4)*4 + r   [measured layout, dtype-independent]
#pragma unroll
        for (int r = 0; r < 4; ++r)
            Qh[(size_t)(r0 + lg * 4 + r) * 64 + ct * 16 + lr] = (_Float16)c[r];
    }
}

// ---- fused per-node pass: entities (attention) + users (weighted mean) ----
// one wave per node; 8 edge-slots x 8 lanes; 8 halves (16B) per lane.
// 2-deep software pipeline: index prefetch distance 2, gather prefetch distance 1.
__global__ __launch_bounds__(256) void k_fused(
    const int* __restrict__ cntE, const int* __restrict__ csrE,
    const _Float16* __restrict__ Qh, const _Float16* __restrict__ Eh,
    const _Float16* __restrict__ Relh,
    _Float16* __restrict__ Ehn, float* __restrict__ Eres,
    const int* __restrict__ cntU, const unsigned long long* __restrict__ csrU2,
    float* __restrict__ Ures)
{
    int wid  = blockIdx.x * 4 + (threadIdx.x >> 6);
    int lane = threadIdx.x & 63;
    int s = lane >> 3, l = lane & 7;            // slot, lane-in-slot
    int c8 = l * 8;                             // this lane's 8 channels

    if (wid < NEN) {
        int row = wid;
        int cnt = cntE[row]; if (cnt > CAPE) cnt = CAPE;
        int beg = row * CAPE, end = beg + cnt;
        P4 q; q.f = *(const float4*)(Qh + (size_t)row * 64 + c8);
        float acc[8] = {0.f,0.f,0.f,0.f,0.f,0.f,0.f,0.f};
        float den = 0.f;
        // pipeline prologue
        int a0 = beg + s;
        int pA = (a0 < end) ? csrE[a0] : 0;
        int pB = (a0 + 8 < end) ? csrE[a0 + 8] : 0;
        P4 ktA, teA, rlA;
        {
            int tail = pA & 0x1FFFF, rt = pA >> 17;
            ktA.f = *(const float4*)(Qh   + (size_t)tail * 64 + c8);
            teA.f = *(const float4*)(Eh   + (size_t)tail * 64 + c8);
            rlA.f = *(const float4*)(Relh + rt * 64 + c8);
        }
        int nit = (cnt + 7) >> 3;
        for (int it = 0; it < nit; ++it) {
            // issue next iteration's gathers first (latency hides under compute)
            P4 ktB, teB, rlB;
            int tailB = pB & 0x1FFFF, rtB = pB >> 17;
            ktB.f = *(const float4*)(Qh   + (size_t)tailB * 64 + c8);
            teB.f = *(const float4*)(Eh   + (size_t)tailB * 64 + c8);
            rlB.f = *(const float4*)(Relh + rtB * 64 + c8);
            int a2 = beg + (it + 2) * 8 + s;
            int pN = (a2 < end) ? csrE[a2] : 0;
            bool act = (beg + it * 8 + s) < end;
            // score via v_dot2_f32_f16
            float sc = 0.f;
#pragma unroll
            for (int i = 0; i < 4; ++i) {
                hv2 km = ktA.h[i] * rlA.h[i];   // v_pk_mul_f16
                sc = __builtin_amdgcn_fdot2(q.h[i], km, sc, false);
            }
            // reduce over the 4 lanes holding this head's channels
            sc += __shfl_xor(sc, 1);
            sc += __shfl_xor(sc, 2);
            float ex = act ? __expf(sc * 0.17677669529663687f) : 0.f;  // 1/sqrt(32)
            den += ex;
#pragma unroll
            for (int i = 0; i < 4; ++i) {
                hv2 vm = teA.h[i] * rlA.h[i];
                acc[2*i]   += ex * (float)vm.x;
                acc[2*i+1] += ex * (float)vm.y;
            }
            ktA = ktB; teA = teB; rlA = rlB; pB = pN;
        }
        // cross-slot totals (slots covered disjoint edge subsets)
#pragma unroll
        for (int k = 0; k < 8; ++k) {
            acc[k] += __shfl_xor(acc[k], 8);
            acc[k] += __shfl_xor(acc[k], 16);
            acc[k] += __shfl_xor(acc[k], 32);
        }
        den += __shfl_xor(den, 8); den += __shfl_xor(den, 16); den += __shfl_xor(den, 32);
        float invd = (den > 0.f) ? 1.f / den : 0.f;   // deferred softmax division
        float ss = 0.f;
#pragma unroll
        for (int k = 0; k < 8; ++k) { acc[k] *= invd; ss += acc[k] * acc[k]; }
        ss += __shfl_xor(ss, 1); ss += __shfl_xor(ss, 2); ss += __shfl_xor(ss, 4);
        float inv = 1.f / fmaxf(sqrtf(ss), 1e-12f);
#pragma unroll
        for (int k = 0; k < 8; ++k) acc[k] *= inv;
        if (s == 0) {                           // one slot writes
            P4 o;
#pragma unroll
            for (int i = 0; i < 4; ++i) { o.h[i].x = (_Float16)acc[2*i]; o.h[i].y = (_Float16)acc[2*i+1]; }
            *(float4*)(Ehn + (size_t)row * 64 + c8) = o.f;
            float4 r0 = *(const float4*)(Eres + (size_t)row * 64 + c8);
            float4 r1 = *(const float4*)(Eres + (size_t)row * 64 + c8 + 4);
            r0.x += acc[0]; r0.y += acc[1]; r0.z += acc[2]; r0.w += acc[3];
            r1.x += acc[4]; r1.y += acc[5]; r1.z += acc[6]; r1.w += acc[7];
            *(float4*)(Eres + (size_t)row * 64 + c8)     = r0;
            *(float4*)(Eres + (size_t)row * 64 + c8 + 4) = r1;
        }
    } else {
        int row = wid - NEN;                    // user node
        int cnt = cntU[row]; if (cnt > CAPU) cnt = CAPU;
        int beg = row * CAPU, end = beg + cnt;
        float acc[8] = {0.f,0.f,0.f,0.f,0.f,0.f,0.f,0.f};
        int a0 = beg + s;
        unsigned long long recA = (a0 < end) ? csrU2[a0] : 0ull;     // rec=0 -> w=+0.0
        unsigned long long recB = (a0 + 8 < end) ? csrU2[a0 + 8] : 0ull;
        P4 teA; teA.f = *(const float4*)(Eh + (size_t)(unsigned)recA * 64 + c8);
        int nit = (cnt + 7) >> 3;
        for (int it = 0; it < nit; ++it) {
            P4 teB; teB.f = *(const float4*)(Eh + (size_t)(unsigned)recB * 64 + c8);
            int a2 = beg + (it + 2) * 8 + s;
            unsigned long long recN = (a2 < end) ? csrU2[a2] : 0ull;
            float wgt = __uint_as_float((unsigned)(recA >> 32));
#pragma unroll
            for (int i = 0; i < 4; ++i) {
                acc[2*i]   += wgt * (float)teA.h[i].x;
                acc[2*i+1] += wgt * (float)teA.h[i].y;
            }
            teA = teB; recA = recB; recB = recN;
        }
#pragma unroll
        for (int k = 0; k < 8; ++k) {
            acc[k] += __shfl_xor(acc[k], 8);
            acc[k] += __shfl_xor(acc[k], 16);
            acc[k] += __shfl_xor(acc[k], 32);
        }
        float ss = 0.f;
#pragma unroll
        for (int k = 0; k < 8; ++k) ss += acc[k] * acc[k];
        ss += __shfl_xor(ss, 1); ss += __shfl_xor(ss, 2); ss += __shfl_xor(ss, 4);
        float inv = 1.f / fmaxf(sqrtf(ss), 1e-12f);
        if (s == 0) {
            float4 r0 = *(const float4*)(Ures + (size_t)row * 64 + c8);
            float4 r1 = *(const float4*)(Ures + (size_t)row * 64 + c8 + 4);
            r0.x += acc[0] * inv; r0.y += acc[1] * inv; r0.z += acc[2] * inv; r0.w += acc[3] * inv;
            r1.x += acc[4] * inv; r1.y += acc[5] * inv; r1.z += acc[6] * inv; r1.w += acc[7] * inv;
            *(float4*)(Ures + (size_t)row * 64 + c8)     = r0;
            *(float4*)(Ures + (size_t)row * 64 + c8 + 4) = r1;
        }
    }
}

extern "C" void kernel_launch(void* const* d_in, const int* in_sizes, int n_in,
                              void* d_out, int out_size, void* d_ws, size_t ws_size,
                              hipStream_t stream)
{
    const float* ue = (const float*)d_in[0];
    const float* ee = (const float*)d_in[1];
    const float* re = (const float*)d_in[2];
    const float* wq = (const float*)d_in[3];
    const float* iw = (const float*)d_in[4];
    const int* eidx  = (const int*)d_in[5];
    const int* etype = (const int*)d_in[6];
    const int* ii    = (const int*)d_in[7];

    float* Eres = (float*)d_out;                 // residuals live in d_out directly
    float* Ures = Eres + (size_t)NEN * CH;

    // ws carve (~87 MB total):
    // [Relh 2KB][Wt 8KB][Qh 12.8M][EhA 12.8M][EhB 12.8M][cntE][cntU][csrE 25.6M][csrU2 25.6M]
    _Float16* Relh = (_Float16*)d_ws;                     // 576 used, 1024 reserved
    _Float16* Wt   = Relh + 1024;                         // 4096 halves (f16 W^T)
    _Float16* Qh   = Wt + 4096;
    _Float16* EhA  = Qh  + (size_t)NEN * CH;
    _Float16* EhB  = EhA + (size_t)NEN * CH;
    int* cntE      = (int*)(EhB + (size_t)NEN * CH);
    int* cntU      = cntE + NEN;
    int* csrE      = cntU + NU;                           // NEN*CAPE ints
    unsigned long long* csrU2 = (unsigned long long*)(csrE + (size_t)NEN * CAPE);

    hipMemsetAsync(cntE, 0, (size_t)(NEN + NU) * sizeof(int), stream);
    k_setup<<<(NEN * CH) / 256, 256, 0, stream>>>(ue, ee, re, wq, iw, eidx, etype, ii,
                                                  EhA, Eres, Ures, Relh, Wt,
                                                  cntE, cntU, csrE, csrU2);

    _Float16* Ehc = EhA;
    _Float16* Ehn = EhB;
    for (int hop = 0; hop < 2; ++hop) {
        k_gemm <<<(NEN + 63) / 64, 256, 0, stream>>>(Ehc, Wt, Qh);
        k_fused<<<(NEN + NU) / 4, 256, 0, stream>>>(cntE, csrE, Qh, Ehc, Relh,
                                                    Ehn, Eres, cntU, csrU2, Ures);
        _Float16* tmp = Ehc; Ehc = Ehn; Ehn = tmp;
    }
}

// Round 2
// 487.940 us; speedup vs baseline: 1.7272x; 1.0429x over previous
//
#include <hip/hip_runtime.h>

#define NU     50000
#define NEN    100000
#define NEDGE  2000000
#define NINTER 1000000
#define CH     64
#define NRELM1 9
#define CAPE   64     // padded CSR bucket capacity per entity (Poisson(20): P(deg>=64)~6e-14/bin)
#define CAPU   64     // padded bucket capacity per user

typedef _Float16 hv2 __attribute__((ext_vector_type(2)));
typedef _Float16 h8  __attribute__((ext_vector_type(8)));
typedef float    f32x4 __attribute__((ext_vector_type(4)));
union P4 { float4 f; hv2 h[4]; };   // 16B = 8 halves

// ---- fused setup: embedding init + W transpose + padded-bucket edge scatter ----
// counters must be zeroed (hipMemsetAsync) before this kernel.
// Edge scatter is 4-wide per thread: 4 independent {load -> atomicAdd -> dependent
// scattered store} chains in flight per lane to hide the ~2000-cycle serial chain
// (atomic round trip to coherence point + scattered sc1 store).
__global__ __launch_bounds__(256) void k_setup(
    const float* __restrict__ ue, const float* __restrict__ ee,
    const float* __restrict__ re, const float* __restrict__ wq,
    const float* __restrict__ iw, const int* __restrict__ eidx,
    const int* __restrict__ etype, const int* __restrict__ ii,
    _Float16* __restrict__ Eh, float* __restrict__ Eres, float* __restrict__ Ures,
    _Float16* __restrict__ Relh, _Float16* __restrict__ Wt,
    int* __restrict__ cntE, int* __restrict__ cntU,
    int* __restrict__ csrE, unsigned long long* __restrict__ csrU2)
{
    int i = blockIdx.x * 256 + threadIdx.x;           // grid covers NEN*CH
    if (i < NEN * CH) {
        float f = ee[i];
        Eh[i] = (_Float16)f;
        Eres[i] = f;
    }
    if (i < NU * CH)     Ures[i] = ue[i];
    if (i < NRELM1 * CH) Relh[i] = (_Float16)re[i];
    if (i < CH * CH)     Wt[(i & 63) * 64 + (i >> 6)] = (_Float16)wq[i];  // Wt[c][k] = W[k][c]

    if (i < NEDGE / 4) {
        int4 h4 = ((const int4*)eidx)[i];
        int4 t4 = ((const int4*)(eidx + NEDGE))[i];
        int4 r4 = ((const int4*)etype)[i];
        int p0 = atomicAdd(&cntE[h4.x], 1);
        int p1 = atomicAdd(&cntE[h4.y], 1);
        int p2 = atomicAdd(&cntE[h4.z], 1);
        int p3 = atomicAdd(&cntE[h4.w], 1);
        if (p0 < CAPE)
            __hip_atomic_store(&csrE[h4.x * CAPE + p0], t4.x | ((r4.x - 1) << 17),
                               __ATOMIC_RELAXED, __HIP_MEMORY_SCOPE_AGENT);
        if (p1 < CAPE)
            __hip_atomic_store(&csrE[h4.y * CAPE + p1], t4.y | ((r4.y - 1) << 17),
                               __ATOMIC_RELAXED, __HIP_MEMORY_SCOPE_AGENT);
        if (p2 < CAPE)
            __hip_atomic_store(&csrE[h4.z * CAPE + p2], t4.z | ((r4.z - 1) << 17),
                               __ATOMIC_RELAXED, __HIP_MEMORY_SCOPE_AGENT);
        if (p3 < CAPE)
            __hip_atomic_store(&csrE[h4.w * CAPE + p3], t4.w | ((r4.w - 1) << 17),
                               __ATOMIC_RELAXED, __HIP_MEMORY_SCOPE_AGENT);
    }
    if (i < NINTER / 4) {
        int4 u4 = ((const int4*)ii)[i];
        int4 e4 = ((const int4*)(ii + NINTER))[i];
        float4 w4 = ((const float4*)iw)[i];
        int q0 = atomicAdd(&cntU[u4.x], 1);
        int q1 = atomicAdd(&cntU[u4.y], 1);
        int q2 = atomicAdd(&cntU[u4.z], 1);
        int q3 = atomicAdd(&cntU[u4.w], 1);
        if (q0 < CAPU)
            __hip_atomic_store(&csrU2[(size_t)u4.x * CAPU + q0],
                               (unsigned long long)(unsigned)e4.x
                             | ((unsigned long long)__float_as_uint(w4.x) << 32),
                               __ATOMIC_RELAXED, __HIP_MEMORY_SCOPE_AGENT);
        if (q1 < CAPU)
            __hip_atomic_store(&csrU2[(size_t)u4.y * CAPU + q1],
                               (unsigned long long)(unsigned)e4.y
                             | ((unsigned long long)__float_as_uint(w4.y) << 32),
                               __ATOMIC_RELAXED, __HIP_MEMORY_SCOPE_AGENT);
        if (q2 < CAPU)
            __hip_atomic_store(&csrU2[(size_t)u4.z * CAPU + q2],
                               (unsigned long long)(unsigned)e4.z
                             | ((unsigned long long)__float_as_uint(w4.z) << 32),
                               __ATOMIC_RELAXED, __HIP_MEMORY_SCOPE_AGENT);
        if (q3 < CAPU)
            __hip_atomic_store(&csrU2[(size_t)u4.w * CAPU + q3],
                               (unsigned long long)(unsigned)e4.w
                             | ((unsigned long long)__float_as_uint(w4.w) << 32),
                               __ATOMIC_RELAXED, __HIP_MEMORY_SCOPE_AGENT);
    }
}

// ---- Qh = Eh @ W via MFMA f16 (f32 accum). Wt is W transposed [c][k], f16.
// one wave = 16 rows x 64 cols; 4 waves/block = 64 rows/block. W stays L1-hot.
__global__ __launch_bounds__(256) void k_gemm(
    const _Float16* __restrict__ Eh, const _Float16* __restrict__ Wt,
    _Float16* __restrict__ Qh)
{
    int w = threadIdx.x >> 6, lane = threadIdx.x & 63;
    int r0 = blockIdx.x * 64 + w * 16;
    if (r0 >= NEN) return;                          // NEN%64==32: last 2 waves idle
    int lr = lane & 15, lg = lane >> 4;
    // A frag (16x32 K-chunk): lane holds row lr, k = kb*32 + lg*8 + j (8 contiguous)
    const _Float16* arow = Eh + (size_t)(r0 + lr) * 64 + lg * 8;
    h8 a0 = *(const h8*)(arow);
    h8 a1 = *(const h8*)(arow + 32);
#pragma unroll
    for (int ct = 0; ct < 4; ++ct) {
        // B frag: lane holds col ct*16+lr, k contiguous -> Wt row read
        const _Float16* brow = Wt + (ct * 16 + lr) * 64 + lg * 8;
        h8 b0 = *(const h8*)(brow);
        h8 b1 = *(const h8*)(brow + 32);
        f32x4 c = {0.f, 0.f, 0.f, 0.f};
        c = __builtin_amdgcn_mfma_f32_16x16x32_f16(a0, b0, c, 0, 0, 0);
        c = __builtin_amdgcn_mfma_f32_16x16x32_f16(a1, b1, c, 0, 0, 0);
        // C/D: col = lane&15, row = (lane>>4)*4 + r   [measured layout, dtype-independent]
#pragma unroll
        for (int r = 0; r < 4; ++r)
            Qh[(size_t)(r0 + lg * 4 + r) * 64 + ct * 16 + lr] = (_Float16)c[r];
    }
}

// ---- fused per-node pass: entities (attention) + users (weighted mean) ----
// one wave per node; 8 edge-slots x 8 lanes; 8 halves (16B) per lane.
// 2-deep software pipeline: index prefetch distance 2, gather prefetch distance 1.
__global__ __launch_bounds__(256) void k_fused(
    const int* __restrict__ cntE, const int* __restrict__ csrE,
    const _Float16* __restrict__ Qh, const _Float16* __restrict__ Eh,
    const _Float16* __restrict__ Relh,
    _Float16* __restrict__ Ehn, float* __restrict__ Eres,
    const int* __restrict__ cntU, const unsigned long long* __restrict__ csrU2,
    float* __restrict__ Ures)
{
    int wid  = blockIdx.x * 4 + (threadIdx.x >> 6);
    int lane = threadIdx.x & 63;
    int s = lane >> 3, l = lane & 7;            // slot, lane-in-slot
    int c8 = l * 8;                             // this lane's 8 channels

    if (wid < NEN) {
        int row = wid;
        int cnt = cntE[row]; if (cnt > CAPE) cnt = CAPE;
        int beg = row * CAPE, end = beg + cnt;
        P4 q; q.f = *(const float4*)(Qh + (size_t)row * 64 + c8);
        float acc[8] = {0.f,0.f,0.f,0.f,0.f,0.f,0.f,0.f};
        float den = 0.f;
        // pipeline prologue
        int a0 = beg + s;
        int pA = (a0 < end) ? csrE[a0] : 0;
        int pB = (a0 + 8 < end) ? csrE[a0 + 8] : 0;
        P4 ktA, teA, rlA;
        {
            int tail = pA & 0x1FFFF, rt = pA >> 17;
            ktA.f = *(const float4*)(Qh   + (size_t)tail * 64 + c8);
            teA.f = *(const float4*)(Eh   + (size_t)tail * 64 + c8);
            rlA.f = *(const float4*)(Relh + rt * 64 + c8);
        }
        int nit = (cnt + 7) >> 3;
        for (int it = 0; it < nit; ++it) {
            // issue next iteration's gathers first (latency hides under compute)
            P4 ktB, teB, rlB;
            int tailB = pB & 0x1FFFF, rtB = pB >> 17;
            ktB.f = *(const float4*)(Qh   + (size_t)tailB * 64 + c8);
            teB.f = *(const float4*)(Eh   + (size_t)tailB * 64 + c8);
            rlB.f = *(const float4*)(Relh + rtB * 64 + c8);
            int a2 = beg + (it + 2) * 8 + s;
            int pN = (a2 < end) ? csrE[a2] : 0;
            bool act = (beg + it * 8 + s) < end;
            // score via v_dot2_f32_f16
            float sc = 0.f;
#pragma unroll
            for (int i = 0; i < 4; ++i) {
                hv2 km = ktA.h[i] * rlA.h[i];   // v_pk_mul_f16
                sc = __builtin_amdgcn_fdot2(q.h[i], km, sc, false);
            }
            // reduce over the 4 lanes holding this head's channels
            sc += __shfl_xor(sc, 1);
            sc += __shfl_xor(sc, 2);
            float ex = act ? __expf(sc * 0.17677669529663687f) : 0.f;  // 1/sqrt(32)
            den += ex;
#pragma unroll
            for (int i = 0; i < 4; ++i) {
                hv2 vm = teA.h[i] * rlA.h[i];
                acc[2*i]   += ex * (float)vm.x;
                acc[2*i+1] += ex * (float)vm.y;
            }
            ktA = ktB; teA = teB; rlA = rlB; pB = pN;
        }
        // cross-slot totals (slots covered disjoint edge subsets)
#pragma unroll
        for (int k = 0; k < 8; ++k) {
            acc[k] += __shfl_xor(acc[k], 8);
            acc[k] += __shfl_xor(acc[k], 16);
            acc[k] += __shfl_xor(acc[k], 32);
        }
        den += __shfl_xor(den, 8); den += __shfl_xor(den, 16); den += __shfl_xor(den, 32);
        float invd = (den > 0.f) ? 1.f / den : 0.f;   // deferred softmax division
        float ss = 0.f;
#pragma unroll
        for (int k = 0; k < 8; ++k) { acc[k] *= invd; ss += acc[k] * acc[k]; }
        ss += __shfl_xor(ss, 1); ss += __shfl_xor(ss, 2); ss += __shfl_xor(ss, 4);
        float inv = 1.f / fmaxf(sqrtf(ss), 1e-12f);
#pragma unroll
        for (int k = 0; k < 8; ++k) acc[k] *= inv;
        if (s == 0) {                           // one slot writes
            P4 o;
#pragma unroll
            for (int i = 0; i < 4; ++i) { o.h[i].x = (_Float16)acc[2*i]; o.h[i].y = (_Float16)acc[2*i+1]; }
            *(float4*)(Ehn + (size_t)row * 64 + c8) = o.f;
            float4 r0 = *(const float4*)(Eres + (size_t)row * 64 + c8);
            float4 r1 = *(const float4*)(Eres + (size_t)row * 64 + c8 + 4);
            r0.x += acc[0]; r0.y += acc[1]; r0.z += acc[2]; r0.w += acc[3];
            r1.x += acc[4]; r1.y += acc[5]; r1.z += acc[6]; r1.w += acc[7];
            *(float4*)(Eres + (size_t)row * 64 + c8)     = r0;
            *(float4*)(Eres + (size_t)row * 64 + c8 + 4) = r1;
        }
    } else {
        int row = wid - NEN;                    // user node
        int cnt = cntU[row]; if (cnt > CAPU) cnt = CAPU;
        int beg = row * CAPU, end = beg + cnt;
        float acc[8] = {0.f,0.f,0.f,0.f,0.f,0.f,0.f,0.f};
        int a0 = beg + s;
        unsigned long long recA = (a0 < end) ? csrU2[a0] : 0ull;     // rec=0 -> w=+0.0
        unsigned long long recB = (a0 + 8 < end) ? csrU2[a0 + 8] : 0ull;
        P4 teA; teA.f = *(const float4*)(Eh + (size_t)(unsigned)recA * 64 + c8);
        int nit = (cnt + 7) >> 3;
        for (int it = 0; it < nit; ++it) {
            P4 teB; teB.f = *(const float4*)(Eh + (size_t)(unsigned)recB * 64 + c8);
            int a2 = beg + (it + 2) * 8 + s;
            unsigned long long recN = (a2 < end) ? csrU2[a2] : 0ull;
            float wgt = __uint_as_float((unsigned)(recA >> 32));
#pragma unroll
            for (int i = 0; i < 4; ++i) {
                acc[2*i]   += wgt * (float)teA.h[i].x;
                acc[2*i+1] += wgt * (float)teA.h[i].y;
            }
            teA = teB; recA = recB; recB = recN;
        }
#pragma unroll
        for (int k = 0; k < 8; ++k) {
            acc[k] += __shfl_xor(acc[k], 8);
            acc[k] += __shfl_xor(acc[k], 16);
            acc[k] += __shfl_xor(acc[k], 32);
        }
        float ss = 0.f;
#pragma unroll
        for (int k = 0; k < 8; ++k) ss += acc[k] * acc[k];
        ss += __shfl_xor(ss, 1); ss += __shfl_xor(ss, 2); ss += __shfl_xor(ss, 4);
        float inv = 1.f / fmaxf(sqrtf(ss), 1e-12f);
        if (s == 0) {
            float4 r0 = *(const float4*)(Ures + (size_t)row * 64 + c8);
            float4 r1 = *(const float4*)(Ures + (size_t)row * 64 + c8 + 4);
            r0.x += acc[0] * inv; r0.y += acc[1] * inv; r0.z += acc[2] * inv; r0.w += acc[3] * inv;
            r1.x += acc[4] * inv; r1.y += acc[5] * inv; r1.z += acc[6] * inv; r1.w += acc[7] * inv;
            *(float4*)(Ures + (size_t)row * 64 + c8)     = r0;
            *(float4*)(Ures + (size_t)row * 64 + c8 + 4) = r1;
        }
    }
}

extern "C" void kernel_launch(void* const* d_in, const int* in_sizes, int n_in,
                              void* d_out, int out_size, void* d_ws, size_t ws_size,
                              hipStream_t stream)
{
    const float* ue = (const float*)d_in[0];
    const float* ee = (const float*)d_in[1];
    const float* re = (const float*)d_in[2];
    const float* wq = (const float*)d_in[3];
    const float* iw = (const float*)d_in[4];
    const int* eidx  = (const int*)d_in[5];
    const int* etype = (const int*)d_in[6];
    const int* ii    = (const int*)d_in[7];

    float* Eres = (float*)d_out;                 // residuals live in d_out directly
    float* Ures = Eres + (size_t)NEN * CH;

    // ws carve (~87 MB total):
    // [Relh 2KB][Wt 8KB][Qh 12.8M][EhA 12.8M][EhB 12.8M][cntE][cntU][csrE 25.6M][csrU2 25.6M]
    _Float16* Relh = (_Float16*)d_ws;                     // 576 used, 1024 reserved
    _Float16* Wt   = Relh + 1024;                         // 4096 halves (f16 W^T)
    _Float16* Qh   = Wt + 4096;
    _Float16* EhA  = Qh  + (size_t)NEN * CH;
    _Float16* EhB  = EhA + (size_t)NEN * CH;
    int* cntE      = (int*)(EhB + (size_t)NEN * CH);
    int* cntU      = cntE + NEN;
    int* csrE      = cntU + NU;                           // NEN*CAPE ints
    unsigned long long* csrU2 = (unsigned long long*)(csrE + (size_t)NEN * CAPE);

    hipMemsetAsync(cntE, 0, (size_t)(NEN + NU) * sizeof(int), stream);
    k_setup<<<(NEN * CH) / 256, 256, 0, stream>>>(ue, ee, re, wq, iw, eidx, etype, ii,
                                                  EhA, Eres, Ures, Relh, Wt,
                                                  cntE, cntU, csrE, csrU2);

    _Float16* Ehc = EhA;
    _Float16* Ehn = EhB;
    for (int hop = 0; hop < 2; ++hop) {
        k_gemm <<<(NEN + 63) / 64, 256, 0, stream>>>(Ehc, Wt, Qh);
        k_fused<<<(NEN + NU) / 4, 256, 0, stream>>>(cntE, csrE, Qh, Ehc, Relh,
                                                    Ehn, Eres, cntU, csrU2, Ures);
        _Float16* tmp = Ehc; Ehc = Ehn; Ehn = tmp;
    }
}

// Round 4
// 471.827 us; speedup vs baseline: 1.7862x; 1.0342x over previous
//
#include <hip/hip_runtime.h>

#define NU     50000
#define NEN    100000
#define NEDGE  2000000
#define NINTER 1000000
#define CH     64
#define NRELM1 9
#define CAPE   64     // padded CSR bucket capacity per entity (Poisson(20): P(deg>=65)~3e-15/bin)
#define CAPU   64     // padded bucket capacity per user

// ---- binned two-pass CSR build ----
#define BINSH   8                                 // 256 nodes per bin
#define NBINE   ((NEN + 255) >> BINSH)            // 391
#define NBINU   ((NU  + 255) >> BINSH)            // 196
#define CAPBE   6144                              // records/bin: mean 5120, sigma~72, +14 sigma
#define CAPBU   6144
#define CHUNK   8192                              // edges per k_bin block
#define NBE_BLK ((NEDGE  + CHUNK - 1) / CHUNK)    // 245
#define NBU_BLK ((NINTER + CHUNK - 1) / CHUNK)    // 123
#define NSTR_E  ((NEN * CH) / 2048)               // 3125 streaming blocks (8 elem/thread)
#define NSTR_U  ((NU * CH + 2047) / 2048)         // 1563

typedef _Float16 hv2 __attribute__((ext_vector_type(2)));
typedef _Float16 h8  __attribute__((ext_vector_type(8)));
typedef float    f32x4 __attribute__((ext_vector_type(4)));
union P4 { float4 f; hv2 h[4]; };   // 16B = 8 halves

// ---- pass 1: coarse binning (LDS histogram, one global atomic per block-bin,
//      grouped run writes) + streaming embedding init as trailing blocks ----
__global__ __launch_bounds__(256) void k_bin(
    const float* __restrict__ ue, const float* __restrict__ ee,
    const float* __restrict__ re, const float* __restrict__ wq,
    const float* __restrict__ iw, const int* __restrict__ eidx,
    const int* __restrict__ etype, const int* __restrict__ ii,
    _Float16* __restrict__ Eh, float* __restrict__ Eres, float* __restrict__ Ures,
    _Float16* __restrict__ Relh, _Float16* __restrict__ Wt,
    int* __restrict__ binCurE, int* __restrict__ binCurU,
    int* __restrict__ binBufE, unsigned long long* __restrict__ binBufU)
{
    __shared__ int hist[NBINE];     // NBINE >= NBINU
    __shared__ int gbase[NBINE];
    int b = blockIdx.x, tid = threadIdx.x;

    if (b < NBE_BLK) {                                   // ---- entity edges ----
        for (int i = tid; i < NBINE; i += 256) hist[i] = 0;
        __syncthreads();
        int base = b * CHUNK;
        int n = NEDGE - base; if (n > CHUNK) n = CHUNK;
        for (int i = tid; i < n; i += 256)
            atomicAdd(&hist[eidx[base + i] >> BINSH], 1);        // LDS atomic
        __syncthreads();
        for (int i = tid; i < NBINE; i += 256) {
            int c = hist[i];
            gbase[i] = c ? atomicAdd(&binCurE[i], c) : 0;        // 1 fabric atomic/block-bin
            hist[i] = 0;                                         // reuse as running offset
        }
        __syncthreads();
        for (int i = tid; i < n; i += 256) {                     // re-read (L2-hot)
            int h  = eidx[base + i];
            int t  = eidx[NEDGE + base + i];
            int rt = etype[base + i] - 1;
            int bin = h >> BINSH;
            int pos = atomicAdd(&hist[bin], 1);
            int g = gbase[bin] + pos;
            if (g < CAPBE)
                __hip_atomic_store(&binBufE[bin * CAPBE + g],
                                   (h & 255) | ((t | (rt << 17)) << 8),
                                   __ATOMIC_RELAXED, __HIP_MEMORY_SCOPE_AGENT);
        }
    } else if (b < NBE_BLK + NBU_BLK) {                  // ---- user-item edges ----
        for (int i = tid; i < NBINU; i += 256) hist[i] = 0;
        __syncthreads();
        int base = (b - NBE_BLK) * CHUNK;
        int n = NINTER - base; if (n > CHUNK) n = CHUNK;
        for (int i = tid; i < n; i += 256)
            atomicAdd(&hist[ii[base + i] >> BINSH], 1);
        __syncthreads();
        for (int i = tid; i < NBINU; i += 256) {
            int c = hist[i];
            gbase[i] = c ? atomicAdd(&binCurU[i], c) : 0;
            hist[i] = 0;
        }
        __syncthreads();
        for (int i = tid; i < n; i += 256) {
            int u = ii[base + i];
            int e = ii[NINTER + base + i];
            unsigned w = __float_as_uint(iw[base + i]);
            int bin = u >> BINSH;
            int pos = atomicAdd(&hist[bin], 1);
            int g = gbase[bin] + pos;
            if (g < CAPBU)
                __hip_atomic_store(&binBufU[bin * CAPBU + g],
                                   (unsigned long long)((u & 255) | (e << 8))
                                 | ((unsigned long long)w << 32),
                                   __ATOMIC_RELAXED, __HIP_MEMORY_SCOPE_AGENT);
        }
    } else {                                             // ---- streaming init ----
        int sb = b - (NBE_BLK + NBU_BLK);
        if (sb < NSTR_E) {
            int i0 = sb * 2048 + tid * 8;
            float4 a = *(const float4*)(ee + i0);
            float4 c = *(const float4*)(ee + i0 + 4);
            *(float4*)(Eres + i0)     = a;
            *(float4*)(Eres + i0 + 4) = c;
            P4 o;
            o.h[0].x = (_Float16)a.x; o.h[0].y = (_Float16)a.y;
            o.h[1].x = (_Float16)a.z; o.h[1].y = (_Float16)a.w;
            o.h[2].x = (_Float16)c.x; o.h[2].y = (_Float16)c.y;
            o.h[3].x = (_Float16)c.z; o.h[3].y = (_Float16)c.w;
            *(float4*)(Eh + i0) = o.f;
        } else if (sb < NSTR_E + NSTR_U) {
            int i0 = (sb - NSTR_E) * 2048 + tid * 8;
            if (i0 < NU * CH) {
                *(float4*)(Ures + i0)     = *(const float4*)(ue + i0);
                *(float4*)(Ures + i0 + 4) = *(const float4*)(ue + i0 + 4);
            }
        } else {
            for (int i = tid; i < NRELM1 * CH; i += 256)          // 576 entries: strided,
                Relh[i] = (_Float16)re[i];                        // NOT tid-guarded (r3 bug)
            for (int i = tid; i < CH * CH; i += 256)
                Wt[(i & 63) * 64 + (i >> 6)] = (_Float16)wq[i];   // Wt[c][k] = W[k][c]
        }
    }
}

// ---- pass 2: per-bin placement. LDS per-node counters (no fabric atomics);
//      csr stores stay within an L2-resident 16-128 KB region -> full-line merge. ----
__global__ __launch_bounds__(256) void k_place(
    const int* __restrict__ binCurE, const int* __restrict__ binBufE,
    const int* __restrict__ binCurU, const unsigned long long* __restrict__ binBufU,
    int* __restrict__ cntE, int* __restrict__ csrE,
    int* __restrict__ cntU, unsigned long long* __restrict__ csrU2)
{
    __shared__ int cnt[256];
    int b = blockIdx.x, tid = threadIdx.x;
    cnt[tid] = 0;
    __syncthreads();
    if (b < NBINE) {
        int n = binCurE[b]; if (n > CAPBE) n = CAPBE;
        const int* buf = binBufE + b * CAPBE;
        for (int i = tid; i < n; i += 256) {
            int rec = buf[i];
            int nl = rec & 255;
            int pos = atomicAdd(&cnt[nl], 1);
            if (pos < CAPE) csrE[((b << BINSH) + nl) * CAPE + pos] = rec >> 8;
        }
        __syncthreads();
        int node = (b << BINSH) + tid;
        if (node < NEN) { int c = cnt[tid]; cntE[node] = c > CAPE ? CAPE : c; }
    } else {
        int ub = b - NBINE;
        int n = binCurU[ub]; if (n > CAPBU) n = CAPBU;
        const unsigned long long* buf = binBufU + ub * CAPBU;
        for (int i = tid; i < n; i += 256) {
            unsigned long long rec = buf[i];
            int nl = (int)rec & 255;
            int pos = atomicAdd(&cnt[nl], 1);
            if (pos < CAPU)
                csrU2[((ub << BINSH) + nl) * CAPU + pos] =
                    ((rec & 0xFFFFFFFFull) >> 8) | (rec & 0xFFFFFFFF00000000ull);
        }
        __syncthreads();
        int node = (ub << BINSH) + tid;
        if (node < NU) { int c = cnt[tid]; cntU[node] = c > CAPU ? CAPU : c; }
    }
}

// ---- Qh = Eh @ W via MFMA f16 (f32 accum). Wt is W transposed [c][k], f16.
// one wave = 16 rows x 64 cols; 4 waves/block = 64 rows/block. W stays L1-hot.
__global__ __launch_bounds__(256) void k_gemm(
    const _Float16* __restrict__ Eh, const _Float16* __restrict__ Wt,
    _Float16* __restrict__ Qh)
{
    int w = threadIdx.x >> 6, lane = threadIdx.x & 63;
    int r0 = blockIdx.x * 64 + w * 16;
    if (r0 >= NEN) return;                          // NEN%64==32: last 2 waves idle
    int lr = lane & 15, lg = lane >> 4;
    // A frag (16x32 K-chunk): lane holds row lr, k = kb*32 + lg*8 + j (8 contiguous)
    const _Float16* arow = Eh + (size_t)(r0 + lr) * 64 + lg * 8;
    h8 a0 = *(const h8*)(arow);
    h8 a1 = *(const h8*)(arow + 32);
#pragma unroll
    for (int ct = 0; ct < 4; ++ct) {
        // B frag: lane holds col ct*16+lr, k contiguous -> Wt row read
        const _Float16* brow = Wt + (ct * 16 + lr) * 64 + lg * 8;
        h8 b0 = *(const h8*)(brow);
        h8 b1 = *(const h8*)(brow + 32);
        f32x4 c = {0.f, 0.f, 0.f, 0.f};
        c = __builtin_amdgcn_mfma_f32_16x16x32_f16(a0, b0, c, 0, 0, 0);
        c = __builtin_amdgcn_mfma_f32_16x16x32_f16(a1, b1, c, 0, 0, 0);
        // C/D: col = lane&15, row = (lane>>4)*4 + r   [measured layout, dtype-independent]
#pragma unroll
        for (int r = 0; r < 4; ++r)
            Qh[(size_t)(r0 + lg * 4 + r) * 64 + ct * 16 + lr] = (_Float16)c[r];
    }
}

// ---- fused per-node pass: entities (attention) + users (weighted mean) ----
// one wave per node; 8 edge-slots x 8 lanes; 8 halves (16B) per lane.
// 2-deep software pipeline: index prefetch distance 2, gather prefetch distance 1.
__global__ __launch_bounds__(256) void k_fused(
    const int* __restrict__ cntE, const int* __restrict__ csrE,
    const _Float16* __restrict__ Qh, const _Float16* __restrict__ Eh,
    const _Float16* __restrict__ Relh,
    _Float16* __restrict__ Ehn, float* __restrict__ Eres,
    const int* __restrict__ cntU, const unsigned long long* __restrict__ csrU2,
    float* __restrict__ Ures)
{
    int wid  = blockIdx.x * 4 + (threadIdx.x >> 6);
    int lane = threadIdx.x & 63;
    int s = lane >> 3, l = lane & 7;            // slot, lane-in-slot
    int c8 = l * 8;                             // this lane's 8 channels

    if (wid < NEN) {
        int row = wid;
        int cnt = cntE[row];
        int beg = row * CAPE, end = beg + cnt;
        P4 q; q.f = *(const float4*)(Qh + (size_t)row * 64 + c8);
        float acc[8] = {0.f,0.f,0.f,0.f,0.f,0.f,0.f,0.f};
        float den = 0.f;
        // pipeline prologue
        int a0 = beg + s;
        int pA = (a0 < end) ? csrE[a0] : 0;
        int pB = (a0 + 8 < end) ? csrE[a0 + 8] : 0;
        P4 ktA, teA, rlA;
        {
            int tail = pA & 0x1FFFF, rt = pA >> 17;
            ktA.f = *(const float4*)(Qh   + (size_t)tail * 64 + c8);
            teA.f = *(const float4*)(Eh   + (size_t)tail * 64 + c8);
            rlA.f = *(const float4*)(Relh + rt * 64 + c8);
        }
        int nit = (cnt + 7) >> 3;
        for (int it = 0; it < nit; ++it) {
            // issue next iteration's gathers first (latency hides under compute)
            P4 ktB, teB, rlB;
            int tailB = pB & 0x1FFFF, rtB = pB >> 17;
            ktB.f = *(const float4*)(Qh   + (size_t)tailB * 64 + c8);
            teB.f = *(const float4*)(Eh   + (size_t)tailB * 64 + c8);
            rlB.f = *(const float4*)(Relh + rtB * 64 + c8);
            int a2 = beg + (it + 2) * 8 + s;
            int pN = (a2 < end) ? csrE[a2] : 0;
            bool act = (beg + it * 8 + s) < end;
            // score via v_dot2_f32_f16
            float sc = 0.f;
#pragma unroll
            for (int i = 0; i < 4; ++i) {
                hv2 km = ktA.h[i] * rlA.h[i];   // v_pk_mul_f16
                sc = __builtin_amdgcn_fdot2(q.h[i], km, sc, false);
            }
            // reduce over the 4 lanes holding this head's channels
            sc += __shfl_xor(sc, 1);
            sc += __shfl_xor(sc, 2);
            float ex = act ? __expf(sc * 0.17677669529663687f) : 0.f;  // 1/sqrt(32)
            den += ex;
#pragma unroll
            for (int i = 0; i < 4; ++i) {
                hv2 vm = teA.h[i] * rlA.h[i];
                acc[2*i]   += ex * (float)vm.x;
                acc[2*i+1] += ex * (float)vm.y;
            }
            ktA = ktB; teA = teB; rlA = rlB; pB = pN;
        }
        // cross-slot totals (slots covered disjoint edge subsets)
#pragma unroll
        for (int k = 0; k < 8; ++k) {
            acc[k] += __shfl_xor(acc[k], 8);
            acc[k] += __shfl_xor(acc[k], 16);
            acc[k] += __shfl_xor(acc[k], 32);
        }
        den += __shfl_xor(den, 8); den += __shfl_xor(den, 16); den += __shfl_xor(den, 32);
        float invd = (den > 0.f) ? 1.f / den : 0.f;   // deferred softmax division
        float ss = 0.f;
#pragma unroll
        for (int k = 0; k < 8; ++k) { acc[k] *= invd; ss += acc[k] * acc[k]; }
        ss += __shfl_xor(ss, 1); ss += __shfl_xor(ss, 2); ss += __shfl_xor(ss, 4);
        float inv = 1.f / fmaxf(sqrtf(ss), 1e-12f);
#pragma unroll
        for (int k = 0; k < 8; ++k) acc[k] *= inv;
        if (s == 0) {                           // one slot writes
            P4 o;
#pragma unroll
            for (int i = 0; i < 4; ++i) { o.h[i].x = (_Float16)acc[2*i]; o.h[i].y = (_Float16)acc[2*i+1]; }
            *(float4*)(Ehn + (size_t)row * 64 + c8) = o.f;
            float4 r0 = *(const float4*)(Eres + (size_t)row * 64 + c8);
            float4 r1 = *(const float4*)(Eres + (size_t)row * 64 + c8 + 4);
            r0.x += acc[0]; r0.y += acc[1]; r0.z += acc[2]; r0.w += acc[3];
            r1.x += acc[4]; r1.y += acc[5]; r1.z += acc[6]; r1.w += acc[7];
            *(float4*)(Eres + (size_t)row * 64 + c8)     = r0;
            *(float4*)(Eres + (size_t)row * 64 + c8 + 4) = r1;
        }
    } else {
        int row = wid - NEN;                    // user node
        int cnt = cntU[row];
        int beg = row * CAPU, end = beg + cnt;
        float acc[8] = {0.f,0.f,0.f,0.f,0.f,0.f,0.f,0.f};
        int a0 = beg + s;
        unsigned long long recA = (a0 < end) ? csrU2[a0] : 0ull;     // rec=0 -> w=+0.0
        unsigned long long recB = (a0 + 8 < end) ? csrU2[a0 + 8] : 0ull;
        P4 teA; teA.f = *(const float4*)(Eh + (size_t)(unsigned)recA * 64 + c8);
        int nit = (cnt + 7) >> 3;
        for (int it = 0; it < nit; ++it) {
            P4 teB; teB.f = *(const float4*)(Eh + (size_t)(unsigned)recB * 64 + c8);
            int a2 = beg + (it + 2) * 8 + s;
            unsigned long long recN = (a2 < end) ? csrU2[a2] : 0ull;
            float wgt = __uint_as_float((unsigned)(recA >> 32));
#pragma unroll
            for (int i = 0; i < 4; ++i) {
                acc[2*i]   += wgt * (float)teA.h[i].x;
                acc[2*i+1] += wgt * (float)teA.h[i].y;
            }
            teA = teB; recA = recB; recB = recN;
        }
#pragma unroll
        for (int k = 0; k < 8; ++k) {
            acc[k] += __shfl_xor(acc[k], 8);
            acc[k] += __shfl_xor(acc[k], 16);
            acc[k] += __shfl_xor(acc[k], 32);
        }
        float ss = 0.f;
#pragma unroll
        for (int k = 0; k < 8; ++k) ss += acc[k] * acc[k];
        ss += __shfl_xor(ss, 1); ss += __shfl_xor(ss, 2); ss += __shfl_xor(ss, 4);
        float inv = 1.f / fmaxf(sqrtf(ss), 1e-12f);
        if (s == 0) {
            float4 r0 = *(const float4*)(Ures + (size_t)row * 64 + c8);
            float4 r1 = *(const float4*)(Ures + (size_t)row * 64 + c8 + 4);
            r0.x += acc[0] * inv; r0.y += acc[1] * inv; r0.z += acc[2] * inv; r0.w += acc[3] * inv;
            r1.x += acc[4] * inv; r1.y += acc[5] * inv; r1.z += acc[6] * inv; r1.w += acc[7] * inv;
            *(float4*)(Ures + (size_t)row * 64 + c8)     = r0;
            *(float4*)(Ures + (size_t)row * 64 + c8 + 4) = r1;
        }
    }
}

extern "C" void kernel_launch(void* const* d_in, const int* in_sizes, int n_in,
                              void* d_out, int out_size, void* d_ws, size_t ws_size,
                              hipStream_t stream)
{
    const float* ue = (const float*)d_in[0];
    const float* ee = (const float*)d_in[1];
    const float* re = (const float*)d_in[2];
    const float* wq = (const float*)d_in[3];
    const float* iw = (const float*)d_in[4];
    const int* eidx  = (const int*)d_in[5];
    const int* etype = (const int*)d_in[6];
    const int* ii    = (const int*)d_in[7];

    float* Eres = (float*)d_out;                 // residuals live in d_out directly
    float* Ures = Eres + (size_t)NEN * CH;

    // ws carve (~90 MB):
    // [Relh 2KB][Wt 8KB][Qh 12.8M][EhA 12.8M][EhB 12.8M][cntE][cntU][csrE 25.6M][csrU2 25.6M][binCur]
    _Float16* Relh = (_Float16*)d_ws;                     // 576 used, 1024 reserved
    _Float16* Wt   = Relh + 1024;                         // 4096 halves (f16 W^T)
    _Float16* Qh   = Wt + 4096;
    _Float16* EhA  = Qh  + (size_t)NEN * CH;
    _Float16* EhB  = EhA + (size_t)NEN * CH;
    int* cntE      = (int*)(EhB + (size_t)NEN * CH);
    int* cntU      = cntE + NEN;
    int* csrE      = cntU + NU;                           // NEN*CAPE ints
    unsigned long long* csrU2 = (unsigned long long*)(csrE + (size_t)NEN * CAPE);
    int* binCurE   = (int*)(csrU2 + (size_t)NU * CAPU);
    int* binCurU   = binCurE + NBINE;
    // bin buffers alias dead space: Qh first written by k_gemm, EhB by hop-0 k_fused
    // (both strictly after k_place reads complete). 9.61 MB < 12.8 MB each.
    int* binBufE   = (int*)Qh;
    unsigned long long* binBufU = (unsigned long long*)EhB;

    hipMemsetAsync(binCurE, 0, (NBINE + NBINU) * sizeof(int), stream);
    k_bin<<<NBE_BLK + NBU_BLK + NSTR_E + NSTR_U + 1, 256, 0, stream>>>(
        ue, ee, re, wq, iw, eidx, etype, ii,
        EhA, Eres, Ures, Relh, Wt, binCurE, binCurU, binBufE, binBufU);
    k_place<<<NBINE + NBINU, 256, 0, stream>>>(binCurE, binBufE, binCurU, binBufU,
                                               cntE, csrE, cntU, csrU2);

    _Float16* Ehc = EhA;
    _Float16* Ehn = EhB;
    for (int hop = 0; hop < 2; ++hop) {
        k_gemm <<<(NEN + 63) / 64, 256, 0, stream>>>(Ehc, Wt, Qh);
        k_fused<<<(NEN + NU) / 4, 256, 0, stream>>>(cntE, csrE, Qh, Ehc, Relh,
                                                    Ehn, Eres, cntU, csrU2, Ures);
        _Float16* tmp = Ehc; Ehc = Ehn; Ehn = tmp;
    }
}

// Round 5
// 433.706 us; speedup vs baseline: 1.9432x; 1.0879x over previous
//
#include <hip/hip_runtime.h>

#define NU     50000
#define NEN    100000
#define NEDGE  2000000
#define NINTER 1000000
#define CH     64
#define NRELM1 9
#define CAPE   64     // padded CSR bucket capacity per entity (Poisson(20): P(deg>=65)~3e-15/bin)
#define CAPU   64     // padded bucket capacity per user

// ---- two-pass CSR build, no fabric atomics / no agent-scope stores ----
#define BINSH   8                                 // 256 nodes per bin
#define NBINE   ((NEN + 255) >> BINSH)            // 391
#define NBINU   ((NU  + 255) >> BINSH)            // 196
#define CHUNKE  8192                              // entity edges per k_bin block
#define CHUNKU  4096                              // user edges per k_bin block (8B recs, 32KB LDS)
#define NBE_BLK ((NEDGE  + CHUNKE - 1) / CHUNKE)  // 245
#define NBU_BLK ((NINTER + CHUNKU - 1) / CHUNKU)  // 245
#define DSTRE   416                               // dir row stride (u32): >=NBINE, 128B multiple
#define DSTRU   224                               // >=NBINU, 128B multiple
#define NSTR_E  ((NEN * CH) / 2048)               // 3125 streaming blocks (8 elem/thread)
#define NSTR_U  ((NU * CH + 2047) / 2048)         // 1563

typedef _Float16 hv2 __attribute__((ext_vector_type(2)));
typedef _Float16 h8  __attribute__((ext_vector_type(8)));
typedef float    f32x4 __attribute__((ext_vector_type(4)));
union P4 { float4 f; hv2 h[4]; };   // 16B = 8 halves

// ---- pass 1: per-chunk bin-sort in LDS, write sorted chunk to block-private
//      region with coalesced plain int4 stores + per-(chunk,bin) directory.
//      Streaming embedding init rides along as trailing blocks. ----
__global__ __launch_bounds__(256) void k_bin(
    const float* __restrict__ ue, const float* __restrict__ ee,
    const float* __restrict__ re, const float* __restrict__ wq,
    const float* __restrict__ iw, const int* __restrict__ eidx,
    const int* __restrict__ etype, const int* __restrict__ ii,
    _Float16* __restrict__ Eh, float* __restrict__ Eres, float* __restrict__ Ures,
    _Float16* __restrict__ Relh, _Float16* __restrict__ Wt,
    unsigned* __restrict__ dirE, unsigned* __restrict__ dirU,
    int* __restrict__ blkBufE, unsigned long long* __restrict__ blkBufU)
{
    __shared__ long long srt64[CHUNKU];   // 32 KB; entity path uses it as int[CHUNKE]
    __shared__ int hist[512];
    __shared__ int sc[512];
    int* srt = (int*)srt64;
    int b = blockIdx.x, tid = threadIdx.x;

    if (b < NBE_BLK) {                                   // ---- entity edges ----
        hist[tid] = 0; hist[tid + 256] = 0;
        __syncthreads();
        int base = b * CHUNKE;
        int n = NEDGE - base; if (n > CHUNKE) n = CHUNKE;
        for (int i = tid; i < n; i += 256)
            atomicAdd(&hist[eidx[base + i] >> BINSH], 1);        // LDS atomic
        __syncthreads();
        sc[tid] = hist[tid]; sc[tid + 256] = hist[tid + 256];
        __syncthreads();
#pragma unroll
        for (int off = 1; off < 512; off <<= 1) {                // inclusive scan, 512
            int v0 = (tid >= off) ? sc[tid - off] : 0;
            int v1 = sc[tid + 256 - off];
            __syncthreads();
            sc[tid] += v0; sc[tid + 256] += v1;
            __syncthreads();
        }
        sc[tid] -= hist[tid]; sc[tid + 256] -= hist[tid + 256];  // exclusive
        __syncthreads();
        for (int i = tid; i < n; i += 256) {                     // re-read (L2-hot), LDS scatter
            int h  = eidx[base + i];
            int t  = eidx[NEDGE + base + i];
            int rt = etype[base + i] - 1;
            int pos = atomicAdd(&sc[h >> BINSH], 1);
            srt[pos] = (h & 255) | ((t | (rt << 17)) << 8);
        }
        __syncthreads();
        int4* dst = (int4*)(blkBufE + b * CHUNKE);               // block-private, coalesced
        const int4* s4 = (const int4*)srt;
        for (int j = tid; j < ((n + 3) >> 2); j += 256) dst[j] = s4[j];
        for (int bin = tid; bin < NBINE; bin += 256)             // dir: (off<<16)|cnt
            dirE[b * DSTRE + bin] =
                ((unsigned)(sc[bin] - hist[bin]) << 16) | (unsigned)hist[bin];
    } else if (b < NBE_BLK + NBU_BLK) {                  // ---- user-item edges ----
        hist[tid] = 0; hist[tid + 256] = 0;
        __syncthreads();
        int ub = b - NBE_BLK;
        int base = ub * CHUNKU;
        int n = NINTER - base; if (n > CHUNKU) n = CHUNKU;
        for (int i = tid; i < n; i += 256)
            atomicAdd(&hist[ii[base + i] >> BINSH], 1);
        __syncthreads();
        sc[tid] = hist[tid]; sc[tid + 256] = hist[tid + 256];
        __syncthreads();
#pragma unroll
        for (int off = 1; off < 512; off <<= 1) {
            int v0 = (tid >= off) ? sc[tid - off] : 0;
            int v1 = sc[tid + 256 - off];
            __syncthreads();
            sc[tid] += v0; sc[tid + 256] += v1;
            __syncthreads();
        }
        sc[tid] -= hist[tid]; sc[tid + 256] -= hist[tid + 256];
        __syncthreads();
        for (int i = tid; i < n; i += 256) {
            int u = ii[base + i];
            int e = ii[NINTER + base + i];
            unsigned w = __float_as_uint(iw[base + i]);
            int pos = atomicAdd(&sc[u >> BINSH], 1);
            srt64[pos] = (unsigned long long)((u & 255) | (e << 8))
                       | ((unsigned long long)w << 32);
        }
        __syncthreads();
        int4* dst = (int4*)(blkBufU + (size_t)ub * CHUNKU);
        const int4* s4 = (const int4*)srt64;
        for (int j = tid; j < ((n + 1) >> 1); j += 256) dst[j] = s4[j];
        for (int bin = tid; bin < NBINU; bin += 256)
            dirU[ub * DSTRU + bin] =
                ((unsigned)(sc[bin] - hist[bin]) << 16) | (unsigned)hist[bin];
    } else {                                             // ---- streaming init ----
        int sb = b - (NBE_BLK + NBU_BLK);
        if (sb < NSTR_E) {
            int i0 = sb * 2048 + tid * 8;
            float4 a = *(const float4*)(ee + i0);
            float4 c = *(const float4*)(ee + i0 + 4);
            *(float4*)(Eres + i0)     = a;
            *(float4*)(Eres + i0 + 4) = c;
            P4 o;
            o.h[0].x = (_Float16)a.x; o.h[0].y = (_Float16)a.y;
            o.h[1].x = (_Float16)a.z; o.h[1].y = (_Float16)a.w;
            o.h[2].x = (_Float16)c.x; o.h[2].y = (_Float16)c.y;
            o.h[3].x = (_Float16)c.z; o.h[3].y = (_Float16)c.w;
            *(float4*)(Eh + i0) = o.f;
        } else if (sb < NSTR_E + NSTR_U) {
            int i0 = (sb - NSTR_E) * 2048 + tid * 8;
            if (i0 < NU * CH) {
                *(float4*)(Ures + i0)     = *(const float4*)(ue + i0);
                *(float4*)(Ures + i0 + 4) = *(const float4*)(ue + i0 + 4);
            }
        } else {
            for (int i = tid; i < NRELM1 * CH; i += 256)
                Relh[i] = (_Float16)re[i];
            for (int i = tid; i < CH * CH; i += 256)
                Wt[(i & 63) * 64 + (i >> 6)] = (_Float16)wq[i];   // Wt[c][k] = W[k][c]
        }
    }
}

// ---- pass 2: per-bin placement. Thread t walks chunk t's segment for this bin
//      (contiguous ~84B reads, L2/L3-cached); LDS per-node counters; plain
//      stores into the bin-private csr region (full-line merge in local L2). ----
__global__ __launch_bounds__(256) void k_place(
    const unsigned* __restrict__ dirE, const int* __restrict__ blkBufE,
    const unsigned* __restrict__ dirU, const unsigned long long* __restrict__ blkBufU,
    int* __restrict__ cntE, int* __restrict__ csrE,
    int* __restrict__ cntU, unsigned long long* __restrict__ csrU2)
{
    __shared__ int cnt[256];
    int b = blockIdx.x, tid = threadIdx.x;
    cnt[tid] = 0;
    __syncthreads();
    if (b < NBINE) {
        if (tid < NBE_BLK) {
            unsigned d = dirE[tid * DSTRE + b];
            int off = d >> 16, c = d & 0xFFFF;
            const int* src = blkBufE + tid * CHUNKE + off;
            for (int i = 0; i < c; ++i) {
                int rec = src[i];
                int nl = rec & 255;
                int pos = atomicAdd(&cnt[nl], 1);
                if (pos < CAPE) csrE[((b << BINSH) + nl) * CAPE + pos] = rec >> 8;
            }
        }
        __syncthreads();
        int node = (b << BINSH) + tid;
        if (node < NEN) { int c = cnt[tid]; cntE[node] = c > CAPE ? CAPE : c; }
    } else {
        int ub = b - NBINE;
        if (tid < NBU_BLK) {
            unsigned d = dirU[tid * DSTRU + ub];
            int off = d >> 16, c = d & 0xFFFF;
            const unsigned long long* src = blkBufU + (size_t)tid * CHUNKU + off;
            for (int i = 0; i < c; ++i) {
                unsigned long long rec = src[i];
                int nl = (int)rec & 255;
                int pos = atomicAdd(&cnt[nl], 1);
                if (pos < CAPU)
                    csrU2[((ub << BINSH) + nl) * CAPU + pos] =
                        ((rec & 0xFFFFFFFFull) >> 8) | (rec & 0xFFFFFFFF00000000ull);
            }
        }
        __syncthreads();
        int node = (ub << BINSH) + tid;
        if (node < NU) { int c = cnt[tid]; cntU[node] = c > CAPU ? CAPU : c; }
    }
}

// ---- Qh = Eh @ W via MFMA f16 (f32 accum). Wt is W transposed [c][k], f16.
// one wave = 16 rows x 64 cols; 4 waves/block = 64 rows/block. W stays L1-hot.
__global__ __launch_bounds__(256) void k_gemm(
    const _Float16* __restrict__ Eh, const _Float16* __restrict__ Wt,
    _Float16* __restrict__ Qh)
{
    int w = threadIdx.x >> 6, lane = threadIdx.x & 63;
    int r0 = blockIdx.x * 64 + w * 16;
    if (r0 >= NEN) return;                          // NEN%64==32: last 2 waves idle
    int lr = lane & 15, lg = lane >> 4;
    // A frag (16x32 K-chunk): lane holds row lr, k = kb*32 + lg*8 + j (8 contiguous)
    const _Float16* arow = Eh + (size_t)(r0 + lr) * 64 + lg * 8;
    h8 a0 = *(const h8*)(arow);
    h8 a1 = *(const h8*)(arow + 32);
#pragma unroll
    for (int ct = 0; ct < 4; ++ct) {
        // B frag: lane holds col ct*16+lr, k contiguous -> Wt row read
        const _Float16* brow = Wt + (ct * 16 + lr) * 64 + lg * 8;
        h8 b0 = *(const h8*)(brow);
        h8 b1 = *(const h8*)(brow + 32);
        f32x4 c = {0.f, 0.f, 0.f, 0.f};
        c = __builtin_amdgcn_mfma_f32_16x16x32_f16(a0, b0, c, 0, 0, 0);
        c = __builtin_amdgcn_mfma_f32_16x16x32_f16(a1, b1, c, 0, 0, 0);
        // C/D: col = lane&15, row = (lane>>4)*4 + r   [measured layout, dtype-independent]
#pragma unroll
        for (int r = 0; r < 4; ++r)
            Qh[(size_t)(r0 + lg * 4 + r) * 64 + ct * 16 + lr] = (_Float16)c[r];
    }
}

// ---- fused per-node pass: entities (attention) + users (weighted mean) ----
// one wave per node; 8 edge-slots x 8 lanes; 8 halves (16B) per lane.
// 2-deep software pipeline: index prefetch distance 2, gather prefetch distance 1.
__global__ __launch_bounds__(256) void k_fused(
    const int* __restrict__ cntE, const int* __restrict__ csrE,
    const _Float16* __restrict__ Qh, const _Float16* __restrict__ Eh,
    const _Float16* __restrict__ Relh,
    _Float16* __restrict__ Ehn, float* __restrict__ Eres,
    const int* __restrict__ cntU, const unsigned long long* __restrict__ csrU2,
    float* __restrict__ Ures)
{
    int wid  = blockIdx.x * 4 + (threadIdx.x >> 6);
    int lane = threadIdx.x & 63;
    int s = lane >> 3, l = lane & 7;            // slot, lane-in-slot
    int c8 = l * 8;                             // this lane's 8 channels

    if (wid < NEN) {
        int row = wid;
        int cnt = cntE[row];
        int beg = row * CAPE, end = beg + cnt;
        P4 q; q.f = *(const float4*)(Qh + (size_t)row * 64 + c8);
        float acc[8] = {0.f,0.f,0.f,0.f,0.f,0.f,0.f,0.f};
        float den = 0.f;
        // pipeline prologue
        int a0 = beg + s;
        int pA = (a0 < end) ? csrE[a0] : 0;
        int pB = (a0 + 8 < end) ? csrE[a0 + 8] : 0;
        P4 ktA, teA, rlA;
        {
            int tail = pA & 0x1FFFF, rt = pA >> 17;
            ktA.f = *(const float4*)(Qh   + (size_t)tail * 64 + c8);
            teA.f = *(const float4*)(Eh   + (size_t)tail * 64 + c8);
            rlA.f = *(const float4*)(Relh + rt * 64 + c8);
        }
        int nit = (cnt + 7) >> 3;
        for (int it = 0; it < nit; ++it) {
            // issue next iteration's gathers first (latency hides under compute)
            P4 ktB, teB, rlB;
            int tailB = pB & 0x1FFFF, rtB = pB >> 17;
            ktB.f = *(const float4*)(Qh   + (size_t)tailB * 64 + c8);
            teB.f = *(const float4*)(Eh   + (size_t)tailB * 64 + c8);
            rlB.f = *(const float4*)(Relh + rtB * 64 + c8);
            int a2 = beg + (it + 2) * 8 + s;
            int pN = (a2 < end) ? csrE[a2] : 0;
            bool act = (beg + it * 8 + s) < end;
            // score via v_dot2_f32_f16
            float sc = 0.f;
#pragma unroll
            for (int i = 0; i < 4; ++i) {
                hv2 km = ktA.h[i] * rlA.h[i];   // v_pk_mul_f16
                sc = __builtin_amdgcn_fdot2(q.h[i], km, sc, false);
            }
            // reduce over the 4 lanes holding this head's channels
            sc += __shfl_xor(sc, 1);
            sc += __shfl_xor(sc, 2);
            float ex = act ? __expf(sc * 0.17677669529663687f) : 0.f;  // 1/sqrt(32)
            den += ex;
#pragma unroll
            for (int i = 0; i < 4; ++i) {
                hv2 vm = teA.h[i] * rlA.h[i];
                acc[2*i]   += ex * (float)vm.x;
                acc[2*i+1] += ex * (float)vm.y;
            }
            ktA = ktB; teA = teB; rlA = rlB; pB = pN;
        }
        // cross-slot totals (slots covered disjoint edge subsets)
#pragma unroll
        for (int k = 0; k < 8; ++k) {
            acc[k] += __shfl_xor(acc[k], 8);
            acc[k] += __shfl_xor(acc[k], 16);
            acc[k] += __shfl_xor(acc[k], 32);
        }
        den += __shfl_xor(den, 8); den += __shfl_xor(den, 16); den += __shfl_xor(den, 32);
        float invd = (den > 0.f) ? 1.f / den : 0.f;   // deferred softmax division
        float ss = 0.f;
#pragma unroll
        for (int k = 0; k < 8; ++k) { acc[k] *= invd; ss += acc[k] * acc[k]; }
        ss += __shfl_xor(ss, 1); ss += __shfl_xor(ss, 2); ss += __shfl_xor(ss, 4);
        float inv = 1.f / fmaxf(sqrtf(ss), 1e-12f);
#pragma unroll
        for (int k = 0; k < 8; ++k) acc[k] *= inv;
        if (s == 0) {                           // one slot writes
            P4 o;
#pragma unroll
            for (int i = 0; i < 4; ++i) { o.h[i].x = (_Float16)acc[2*i]; o.h[i].y = (_Float16)acc[2*i+1]; }
            *(float4*)(Ehn + (size_t)row * 64 + c8) = o.f;
            float4 r0 = *(const float4*)(Eres + (size_t)row * 64 + c8);
            float4 r1 = *(const float4*)(Eres + (size_t)row * 64 + c8 + 4);
            r0.x += acc[0]; r0.y += acc[1]; r0.z += acc[2]; r0.w += acc[3];
            r1.x += acc[4]; r1.y += acc[5]; r1.z += acc[6]; r1.w += acc[7];
            *(float4*)(Eres + (size_t)row * 64 + c8)     = r0;
            *(float4*)(Eres + (size_t)row * 64 + c8 + 4) = r1;
        }
    } else {
        int row = wid - NEN;                    // user node
        int cnt = cntU[row];
        int beg = row * CAPU, end = beg + cnt;
        float acc[8] = {0.f,0.f,0.f,0.f,0.f,0.f,0.f,0.f};
        int a0 = beg + s;
        unsigned long long recA = (a0 < end) ? csrU2[a0] : 0ull;     // rec=0 -> w=+0.0
        unsigned long long recB = (a0 + 8 < end) ? csrU2[a0 + 8] : 0ull;
        P4 teA; teA.f = *(const float4*)(Eh + (size_t)(unsigned)recA * 64 + c8);
        int nit = (cnt + 7) >> 3;
        for (int it = 0; it < nit; ++it) {
            P4 teB; teB.f = *(const float4*)(Eh + (size_t)(unsigned)recB * 64 + c8);
            int a2 = beg + (it + 2) * 8 + s;
            unsigned long long recN = (a2 < end) ? csrU2[a2] : 0ull;
            float wgt = __uint_as_float((unsigned)(recA >> 32));
#pragma unroll
            for (int i = 0; i < 4; ++i) {
                acc[2*i]   += wgt * (float)teA.h[i].x;
                acc[2*i+1] += wgt * (float)teA.h[i].y;
            }
            teA = teB; recA = recB; recB = recN;
        }
#pragma unroll
        for (int k = 0; k < 8; ++k) {
            acc[k] += __shfl_xor(acc[k], 8);
            acc[k] += __shfl_xor(acc[k], 16);
            acc[k] += __shfl_xor(acc[k], 32);
        }
        float ss = 0.f;
#pragma unroll
        for (int k = 0; k < 8; ++k) ss += acc[k] * acc[k];
        ss += __shfl_xor(ss, 1); ss += __shfl_xor(ss, 2); ss += __shfl_xor(ss, 4);
        float inv = 1.f / fmaxf(sqrtf(ss), 1e-12f);
        if (s == 0) {
            float4 r0 = *(const float4*)(Ures + (size_t)row * 64 + c8);
            float4 r1 = *(const float4*)(Ures + (size_t)row * 64 + c8 + 4);
            r0.x += acc[0] * inv; r0.y += acc[1] * inv; r0.z += acc[2] * inv; r0.w += acc[3] * inv;
            r1.x += acc[4] * inv; r1.y += acc[5] * inv; r1.z += acc[6] * inv; r1.w += acc[7] * inv;
            *(float4*)(Ures + (size_t)row * 64 + c8)     = r0;
            *(float4*)(Ures + (size_t)row * 64 + c8 + 4) = r1;
        }
    }
}

extern "C" void kernel_launch(void* const* d_in, const int* in_sizes, int n_in,
                              void* d_out, int out_size, void* d_ws, size_t ws_size,
                              hipStream_t stream)
{
    const float* ue = (const float*)d_in[0];
    const float* ee = (const float*)d_in[1];
    const float* re = (const float*)d_in[2];
    const float* wq = (const float*)d_in[3];
    const float* iw = (const float*)d_in[4];
    const int* eidx  = (const int*)d_in[5];
    const int* etype = (const int*)d_in[6];
    const int* ii    = (const int*)d_in[7];

    float* Eres = (float*)d_out;                 // residuals live in d_out directly
    float* Ures = Eres + (size_t)NEN * CH;

    // ws carve (~91 MB):
    // [Relh 2KB][Wt 8KB][Qh 12.8M][EhA 12.8M][EhB 12.8M][cntE][cntU][csrE 25.6M][csrU2 25.6M][dirE][dirU]
    _Float16* Relh = (_Float16*)d_ws;                     // 576 used, 1024 reserved
    _Float16* Wt   = Relh + 1024;                         // 4096 halves (f16 W^T)
    _Float16* Qh   = Wt + 4096;
    _Float16* EhA  = Qh  + (size_t)NEN * CH;
    _Float16* EhB  = EhA + (size_t)NEN * CH;
    int* cntE      = (int*)(EhB + (size_t)NEN * CH);
    int* cntU      = cntE + NEN;
    int* csrE      = cntU + NU;                           // NEN*CAPE ints
    unsigned long long* csrU2 = (unsigned long long*)(csrE + (size_t)NEN * CAPE);
    unsigned* dirE = (unsigned*)(csrU2 + (size_t)NU * CAPU);   // 245*416 u32
    unsigned* dirU = dirE + NBE_BLK * DSTRE;                   // 245*224 u32
    // chunk buffers alias dead space: Qh first written by k_gemm, EhB by hop-0
    // k_fused (both strictly after k_place reads complete). ~8 MB < 12.8 MB each.
    int* blkBufE   = (int*)Qh;                            // NBE_BLK*CHUNKE ints
    unsigned long long* blkBufU = (unsigned long long*)EhB;    // NBU_BLK*CHUNKU u64

    k_bin<<<NBE_BLK + NBU_BLK + NSTR_E + NSTR_U + 1, 256, 0, stream>>>(
        ue, ee, re, wq, iw, eidx, etype, ii,
        EhA, Eres, Ures, Relh, Wt, dirE, dirU, blkBufE, blkBufU);
    k_place<<<NBINE + NBINU, 256, 0, stream>>>(dirE, blkBufE, dirU, blkBufU,
                                               cntE, csrE, cntU, csrU2);

    _Float16* Ehc = EhA;
    _Float16* Ehn = EhB;
    for (int hop = 0; hop < 2; ++hop) {
        k_gemm <<<(NEN + 63) / 64, 256, 0, stream>>>(Ehc, Wt, Qh);
        k_fused<<<(NEN + NU) / 4, 256, 0, stream>>>(cntE, csrE, Qh, Ehc, Relh,
                                                    Ehn, Eres, cntU, csrU2, Ures);
        _Float16* tmp = Ehc; Ehc = Ehn; Ehn = tmp;
    }
}